// Round 6
// baseline (459.416 us; speedup 1.0000x reference)
//
#include <hip/hip_runtime.h>

typedef short  short8   __attribute__((ext_vector_type(8)));
typedef float  floatx4  __attribute__((ext_vector_type(4)));
typedef unsigned int uintx2 __attribute__((ext_vector_type(2)));

#define LOG2E_X2 2.8853900817779268f

// Inputs pre-scaled by 2*log2(e) (folded into W1/b1): tanh(a)=1-2/(exp2(y)+1).
__device__ __forceinline__ float tanh_pre(float y) {
    float e = __builtin_amdgcn_exp2f(y);
    return 1.0f - 2.0f * __builtin_amdgcn_rcpf(1.0f + e);
}

__device__ __forceinline__ unsigned short bf16rne(float f) {   // setup only
    unsigned u = __float_as_uint(f);
    u += 0x7FFFu + ((u >> 16) & 1u);
    return (unsigned short)(u >> 16);
}

// RNE-pack two f32 -> dword of 2 bf16 (lo=a, hi=b).
#if __has_builtin(__builtin_amdgcn_cvt_pk_bf16_f32)
__device__ __forceinline__ unsigned pk2(float a, float b) {
    auto r = __builtin_amdgcn_cvt_pk_bf16_f32(a, b);
    unsigned u; __builtin_memcpy(&u, &r, 4);
    return u;
}
#else
__device__ __forceinline__ unsigned pk2(float a, float b) {
    unsigned r;
    asm("v_cvt_pk_bf16_f32 %0, %1, %2" : "=v"(r) : "v"(a), "v"(b));
    return r;
}
#endif

// Unpack 4 bf16 (packed lo/hi per dword) -> floatx4, exact.
__device__ __forceinline__ floatx4 unpk4(uintx2 u) {
    floatx4 r;
    r[0] = __uint_as_float(u.x << 16);
    r[1] = __uint_as_float(u.x & 0xffff0000u);
    r[2] = __uint_as_float(u.y << 16);
    r[3] = __uint_as_float(u.y & 0xffff0000u);
    return r;
}

// Round 9: RESUBMIT of Round 8 (container infra failure, no kernel verdict).
// R6 base + tanh REBALANCE. G1 waves were the barrier-critical path (~1300+
// cyc/interval, transcendental-dominated) while G2 waves idled (~300 cyc).
// G1 tanh+packs only ht 0,1 (32 of 64 channels) and publishes ht 2,3 raw f32
// accs to LDS Raw[stream]; G2 waves tanh+pack disjoint 16x64 slices of Raw
// into Hs at the start of the next interval; a mid-interval barrier precedes
// GEMM2. Work conserved (no duplication), VALU issue spread across all 8
// waves. Same per-value arithmetic as R6 -> bit-identical output.
// Interval: start-barrier -> [HELP(S) || G1(S')] -> mid-barrier -> [G2(S)].
// Barriers matched across the wave-role branch: 257 each side.
// LDS: 80928 B/block -> 81408 after 512B granularity; x2 blocks = 162816
// <= 163840 (2 blocks/CU preserved; OccupancyPercent is the tripwire).
__global__ __launch_bounds__(512, 4) void ode_mfma(
    const float* __restrict__ s_in,  const float* __restrict__ t_in,
    const float* __restrict__ phi_in,const float* __restrict__ bfr_in,
    const float* __restrict__ w1_in, const float* __restrict__ b1_in,
    const float* __restrict__ w2_in, const float* __restrict__ b2_in,
    float* __restrict__ out)
{
    const int tid  = threadIdx.x;
    const int w    = tid >> 6;         // wave 0..7
    const int lane = tid & 63;
    const int l15  = lane & 15;
    const int q    = lane >> 4;
    const int wg   = blockIdx.x;
    const int sb   = wg >> 5;
    const int n0   = (wg & 31) << 6;
    const int rowg0 = sb * 2048 + n0;

    __shared__ __align__(16) unsigned short Atile[64][104];
    __shared__ __align__(16) unsigned short Hs[64][264];
    __shared__ __align__(16) float Raw[2][32][132];   // [stream][local row][chan 0..127 +pad]
    __shared__ float dls[8];

    // Phi -> Atile cols 64..95 (all 512 threads, one floatx4 each; written once)
    {
        int row = tid >> 3, cc = tid & 7;
        floatx4 p = *(const floatx4*)(phi_in + (rowg0 + row) * 32 + cc * 4);
        uintx2 px = { pk2(p[0], p[1]), pk2(p[2], p[3]) };
        *(uintx2*)&Atile[row][64 + cc * 4] = px;
    }
    if (tid < 8) dls[tid] = t_in[sb * 9 + tid + 1] - t_in[sb * 9 + tid];

// ---- G1 producer: GEMM1 for stream tiles (RT0,RT0+1), 64 h-channels.
// tanh+pack ht 0,1 directly to Hs; publish ht 2,3 raw f32 to Raw[S].
#define DO_G1P(RT0, S)                                                          \
    {                                                                           \
        floatx4 acc1[4][2];                                                     \
        {                                                                       \
            short8 xb[2];                                                       \
            _Pragma("unroll")                                                   \
            for (int r2 = 0; r2 < 2; ++r2)                                      \
                xb[r2] = *(const short8*)&Atile[(RT0 + r2) * 16 + l15][q * 8];  \
            _Pragma("unroll")                                                   \
            for (int ht = 0; ht < 4; ++ht)                                      \
                _Pragma("unroll")                                               \
                for (int r2 = 0; r2 < 2; ++r2)                                  \
                    acc1[ht][r2] = __builtin_amdgcn_mfma_f32_16x16x32_bf16(     \
                        w1f[ht][0], xb[r2], bbf[ht], 0, 0, 0);                  \
        }                                                                       \
        _Pragma("unroll")                                                       \
        for (int kk = 1; kk < 3; ++kk) {                                        \
            short8 xb[2];                                                       \
            _Pragma("unroll")                                                   \
            for (int r2 = 0; r2 < 2; ++r2)                                      \
                xb[r2] = *(const short8*)&Atile[(RT0 + r2) * 16 + l15][kk * 32 + q * 8]; \
            _Pragma("unroll")                                                   \
            for (int ht = 0; ht < 4; ++ht)                                      \
                _Pragma("unroll")                                               \
                for (int r2 = 0; r2 < 2; ++r2)                                  \
                    acc1[ht][r2] = __builtin_amdgcn_mfma_f32_16x16x32_bf16(     \
                        w1f[ht][kk], xb[r2], acc1[ht][r2], 0, 0, 0);            \
        }                                                                       \
        _Pragma("unroll")                                                       \
        for (int ht = 0; ht < 2; ++ht)                                          \
            _Pragma("unroll")                                                   \
            for (int r2 = 0; r2 < 2; ++r2) {                                    \
                uintx2 hp = { pk2(tanh_pre(acc1[ht][r2][0]), tanh_pre(acc1[ht][r2][1])), \
                              pk2(tanh_pre(acc1[ht][r2][2]), tanh_pre(acc1[ht][r2][3])) }; \
                *(uintx2*)&Hs[(RT0 + r2) * 16 + l15][hb0 + ht * 16 + q * 4] = hp; \
            }                                                                   \
        _Pragma("unroll")                                                       \
        for (int ht = 2; ht < 4; ++ht)                                          \
            _Pragma("unroll")                                                   \
            for (int r2 = 0; r2 < 2; ++r2)                                      \
                *(floatx4*)&Raw[S][r2 * 16 + l15][(hb0 >> 1) + (ht - 2) * 16 + q * 4] = acc1[ht][r2]; \
    }

// ---- Helper (runs on G2 waves, pre-mid-barrier): tanh+pack this wave's
// disjoint 16-row x 64-chan slice of Raw[S] into Hs offloaded columns.
// raw chan c -> global channel ((c>>5)*64 + 32 + (c&31)).
#define DO_HELP(S)                                                              \
    {                                                                           \
        const int hrow = (S) * 32 + rt_rel * 16 + l15;                          \
        _Pragma("unroll")                                                       \
        for (int k = 0; k < 4; ++k) {                                           \
            const int c = dp * 2 + q * 16 + k * 4;                              \
            floatx4 v = *(const floatx4*)&Raw[S][rt_rel * 16 + l15][c];         \
            uintx2 hp = { pk2(tanh_pre(v[0]), tanh_pre(v[1])),                  \
                          pk2(tanh_pre(v[2]), tanh_pre(v[3])) };                \
            const int g = ((c >> 5) << 6) + 32 + (c & 31);                      \
            *(uintx2*)&Hs[hrow][g] = hp;                                        \
        }                                                                       \
    }

// ---- G2 consumer: stream SI, tile rt = SI*2+rt_rel, d cols dp..dp+32.
#define DO_G2(SI)                                                               \
    {                                                                           \
        const int rt = (SI) * 2 + rt_rel;                                       \
        const unsigned short* hrow = &Hs[rt * 16 + l15][0];                     \
        floatx4 acc2a, acc2b;                                                   \
        {                                                                       \
            short8 hb = *(const short8*)&hrow[q * 8];                           \
            acc2a = __builtin_amdgcn_mfma_f32_16x16x32_bf16(                    \
                w2f[0][0], hb, unpk4(fpk[SI][0]), 0, 0, 0);                     \
            acc2b = __builtin_amdgcn_mfma_f32_16x16x32_bf16(                    \
                w2f[1][0], hb, unpk4(fpk[SI][1]), 0, 0, 0);                     \
        }                                                                       \
        _Pragma("unroll")                                                       \
        for (int kk = 1; kk < 8; ++kk) {                                        \
            short8 hb = *(const short8*)&hrow[kk * 32 + q * 8];                 \
            acc2a = __builtin_amdgcn_mfma_f32_16x16x32_bf16(                    \
                w2f[0][kk], hb, acc2a, 0, 0, 0);                                \
            acc2b = __builtin_amdgcn_mfma_f32_16x16x32_bf16(                    \
                w2f[1][kk], hb, acc2b, 0, 0, 0);                                \
        }                                                                       \
        _Pragma("unroll")                                                       \
        for (int h = 0; h < 2; ++h) {                                           \
            floatx4 kv = (h == 0 ? acc2a : acc2b) * dlt;                        \
            floatx4 xe;                                                         \
            if (sub == 0)      { kacc[SI][h] = kv;            xe = xv[SI][h] + 0.25f * kv; } \
            else if (sub == 1) { kacc[SI][h] += 2.0f * kv;    xe = xv[SI][h] + 0.25f * kv; } \
            else if (sub == 2) { kacc[SI][h] += 2.0f * kv;    xe = xv[SI][h] + 0.5f  * kv; } \
            else               { xv[SI][h] += (kacc[SI][h] + kv) * (1.0f / 12.0f); xe = xv[SI][h]; } \
            uintx2 px = { pk2(xe[0], xe[1]), pk2(xe[2], xe[3]) };               \
            *(uintx2*)&Atile[rt * 16 + l15][dp + h * 16 + q * 4] = px;          \
        }                                                                       \
        if (ii == 7) {                                                          \
            const size_t ob = (size_t)((sb * 8 + blk) * 2048 + n0 + rt * 16 + l15) * 64; \
            _Pragma("unroll")                                                   \
            for (int h = 0; h < 2; ++h)                                         \
                *(floatx4*)(out + ob + dp + h * 16 + q * 4) = xv[SI][h];        \
        }                                                                       \
    }

    if (w < 4) {
        // ================= G1 producer waves =================
        const int hb0 = w * 64;
        short8 w1f[4][3];
#pragma unroll
        for (int ht = 0; ht < 4; ++ht)
#pragma unroll
            for (int kk = 0; kk < 3; ++kk) {
                short8 f;
#pragma unroll
                for (int j = 0; j < 8; ++j) {
                    int k = kk * 32 + q * 8 + j;
                    int hc = hb0 + ht * 16 + l15;
                    f[j] = (short)bf16rne(w1_in[k * 256 + hc] * LOG2E_X2);
                }
                w1f[ht][kk] = f;
            }
        floatx4 bbf[4];
#pragma unroll
        for (int ht = 0; ht < 4; ++ht) {
            floatx4 v = *(const floatx4*)(b1_in + hb0 + ht * 16 + q * 4);
            bbf[ht] = v * LOG2E_X2;
        }

        __syncthreads();                 // init barrier: Atile-x/Phi ready
        DO_G1P(0, 0)                     // prologue: Hs(A,0) ht01 + Raw[A]
#pragma unroll 1
        for (int it = 0; it < 64; ++it) {
            __syncthreads();             // start1
            DO_G1P(2, 1)                 // stream B substep it
            __syncthreads();             // mid1 (helpers' Hs(A) now visible)
            __syncthreads();             // start2
            if (it < 63) { DO_G1P(0, 0) }// stream A substep it+1
            __syncthreads();             // mid2
        }
    } else {
        // ================= G2 consumer waves =================
        const int g2 = w - 4;
        const int rt_rel = g2 >> 1;
        const int dp = (g2 & 1) * 32;
        short8 w2f[2][8];                // [d-half][kk]
#pragma unroll
        for (int h = 0; h < 2; ++h)
#pragma unroll
            for (int kk = 0; kk < 8; ++kk) {
                short8 f;
#pragma unroll
                for (int j = 0; j < 8; ++j) {
                    int k = kk * 32 + q * 8 + j;
                    f[j] = (short)bf16rne(w2_in[k * 64 + dp + h * 16 + l15]);
                }
                w2f[h][kk] = f;
            }

        floatx4 xv[2][2], kacc[2][2];
        uintx2 fpk[2][2];                // b2+bfr, bf16-packed C-seeds
#pragma unroll
        for (int si = 0; si < 2; ++si) {
            const int rt = si * 2 + rt_rel;
            const int rg = rowg0 + rt * 16 + l15;
#pragma unroll
            for (int h = 0; h < 2; ++h) {
                const int dh = dp + h * 16 + q * 4;
                xv[si][h] = *(const floatx4*)(s_in + rg * 64 + dh);
                floatx4 fb = *(const floatx4*)(b2_in + dh)
                           + *(const floatx4*)(bfr_in + rg * 64 + dh);
                fpk[si][h] = (uintx2){ pk2(fb[0], fb[1]), pk2(fb[2], fb[3]) };
                uintx2 px = { pk2(xv[si][h][0], xv[si][h][1]),
                              pk2(xv[si][h][2], xv[si][h][3]) };
                *(uintx2*)&Atile[rt * 16 + l15][dh] = px;
            }
        }

        __syncthreads();                 // init barrier: Atile-x/Phi ready
#pragma unroll 1
        for (int blk = 0; blk < 8; ++blk) {
            const float dlt = dls[blk];
#pragma unroll 1
            for (int ii = 0; ii < 8; ++ii) {
                const int sub = ii & 3;
                __syncthreads();         // start1: Raw[A]/Hs(A)ht01/AtileB ready
                DO_HELP(0)               // finish Hs(A) offloaded channels
                __syncthreads();         // mid1: Hs(A) complete
                DO_G2(0)                 // stream A: GEMM2 + RK4 epilogue
                __syncthreads();         // start2: Raw[B]/Hs(B)ht01 ready
                DO_HELP(1)               // finish Hs(B) offloaded channels
                __syncthreads();         // mid2: Hs(B) complete
                DO_G2(1)                 // stream B: GEMM2 + RK4 epilogue
            }
        }
    }
#undef DO_G1P
#undef DO_HELP
#undef DO_G2
}

extern "C" void kernel_launch(void* const* d_in, const int* in_sizes, int n_in,
                              void* d_out, int out_size, void* d_ws, size_t ws_size,
                              hipStream_t stream) {
    const float* s_in  = (const float*)d_in[0];
    const float* t_in  = (const float*)d_in[1];
    const float* phi   = (const float*)d_in[2];
    const float* bfr   = (const float*)d_in[3];
    const float* w1    = (const float*)d_in[4];
    const float* b1    = (const float*)d_in[5];
    const float* w2    = (const float*)d_in[6];
    const float* b2    = (const float*)d_in[7];
    ode_mfma<<<512, 512, 0, stream>>>(s_in, t_in, phi, bfr, w1, b1, w2, b2, (float*)d_out);
}

// Round 7
// 368.716 us; speedup vs baseline: 1.2460x; 1.2460x over previous
//
#include <hip/hip_runtime.h>

typedef short  short8   __attribute__((ext_vector_type(8)));
typedef float  floatx4  __attribute__((ext_vector_type(4)));
typedef unsigned int uintx2 __attribute__((ext_vector_type(2)));

#define LOG2E_X2 2.8853900817779268f

// Inputs pre-scaled by 2*log2(e) (folded into W1/b1): tanh(a)=1-2/(exp2(y)+1).
__device__ __forceinline__ float tanh_pre(float y) {
    float e = __builtin_amdgcn_exp2f(y);
    return 1.0f - 2.0f * __builtin_amdgcn_rcpf(1.0f + e);
}

__device__ __forceinline__ unsigned short bf16rne(float f) {   // setup only
    unsigned u = __float_as_uint(f);
    u += 0x7FFFu + ((u >> 16) & 1u);
    return (unsigned short)(u >> 16);
}

// RNE-pack two f32 -> dword of 2 bf16 (lo=a, hi=b).
#if __has_builtin(__builtin_amdgcn_cvt_pk_bf16_f32)
__device__ __forceinline__ unsigned pk2(float a, float b) {
    auto r = __builtin_amdgcn_cvt_pk_bf16_f32(a, b);
    unsigned u; __builtin_memcpy(&u, &r, 4);
    return u;
}
#else
__device__ __forceinline__ unsigned pk2(float a, float b) {
    unsigned r;
    asm("v_cvt_pk_bf16_f32 %0, %1, %2" : "=v"(r) : "v"(a), "v"(b));
    return r;
}
#endif

// Unpack 4 bf16 (packed lo/hi per dword) -> floatx4, exact.
__device__ __forceinline__ floatx4 unpk4(uintx2 u) {
    floatx4 r;
    r[0] = __uint_as_float(u.x << 16);
    r[1] = __uint_as_float(u.x & 0xffff0000u);
    r[2] = __uint_as_float(u.y << 16);
    r[3] = __uint_as_float(u.y & 0xffff0000u);
    return r;
}

// Round 10: R6 structure (2 barriers/substep, G1(S') || G2(S)) + BARRIER-FREE
// tanh rebalance. R8/R9's mid-barrier serialized GEMM1/GEMM2 (252->427us);
// here G1 publishes ht2,3 raw f32 accs to Raw[S] at the SAME start-barrier
// that publishes Hs, and each G2 wave tanh+packs those channels IN REGISTERS
// as it builds its own B-fragments for odd kk-blocks (dup across the dp-pair,
// absorbed by G2 idle capacity). Per-lane tanh: 64/0 -> 32/32 G1/G2. No extra
// barriers; MFMA order kk=0..7 preserved; every rounded value identical to R6
// -> bit-identical output (absmax 0.03125).
// Hs compacted to kept channels {g: (g&63)<32}: hs_c=(g>>6)*32+(g&31).
// Raw holds offloaded {(g&63)>=32}:            raw_c=(g>>6)*32+(g&31).
// LDS: 13312 + 17408 + 33792 + 32 = 64544 B -> 2 blocks/CU preserved.
__global__ __launch_bounds__(512, 4) void ode_mfma(
    const float* __restrict__ s_in,  const float* __restrict__ t_in,
    const float* __restrict__ phi_in,const float* __restrict__ bfr_in,
    const float* __restrict__ w1_in, const float* __restrict__ b1_in,
    const float* __restrict__ w2_in, const float* __restrict__ b2_in,
    float* __restrict__ out)
{
    const int tid  = threadIdx.x;
    const int w    = tid >> 6;         // wave 0..7
    const int lane = tid & 63;
    const int l15  = lane & 15;
    const int q    = lane >> 4;
    const int wg   = blockIdx.x;
    const int sb   = wg >> 5;
    const int n0   = (wg & 31) << 6;
    const int rowg0 = sb * 2048 + n0;

    __shared__ __align__(16) unsigned short Atile[64][104];
    __shared__ __align__(16) unsigned short Hs[64][136];   // kept channels only
    __shared__ __align__(16) float Raw[2][32][132];        // [stream][row][raw chan]
    __shared__ float dls[8];

    // Phi -> Atile cols 64..95 (all 512 threads, one floatx4 each; written once)
    {
        int row = tid >> 3, cc = tid & 7;
        floatx4 p = *(const floatx4*)(phi_in + (rowg0 + row) * 32 + cc * 4);
        uintx2 px = { pk2(p[0], p[1]), pk2(p[2], p[3]) };
        *(uintx2*)&Atile[row][64 + cc * 4] = px;
    }
    if (tid < 8) dls[tid] = t_in[sb * 9 + tid + 1] - t_in[sb * 9 + tid];

// ---- G1 producer: GEMM1 for stream tiles (RT0,RT0+1), 64 h-channels.
// tanh+pack ht 0,1 -> compact Hs; publish ht 2,3 raw f32 -> Raw[S].
#define DO_G1P(RT0, S)                                                          \
    {                                                                           \
        floatx4 acc1[4][2];                                                     \
        {                                                                       \
            short8 xb[2];                                                       \
            _Pragma("unroll")                                                   \
            for (int r2 = 0; r2 < 2; ++r2)                                      \
                xb[r2] = *(const short8*)&Atile[(RT0 + r2) * 16 + l15][q * 8];  \
            _Pragma("unroll")                                                   \
            for (int ht = 0; ht < 4; ++ht)                                      \
                _Pragma("unroll")                                               \
                for (int r2 = 0; r2 < 2; ++r2)                                  \
                    acc1[ht][r2] = __builtin_amdgcn_mfma_f32_16x16x32_bf16(     \
                        w1f[ht][0], xb[r2], bbf[ht], 0, 0, 0);                  \
        }                                                                       \
        _Pragma("unroll")                                                       \
        for (int kk = 1; kk < 3; ++kk) {                                        \
            short8 xb[2];                                                       \
            _Pragma("unroll")                                                   \
            for (int r2 = 0; r2 < 2; ++r2)                                      \
                xb[r2] = *(const short8*)&Atile[(RT0 + r2) * 16 + l15][kk * 32 + q * 8]; \
            _Pragma("unroll")                                                   \
            for (int ht = 0; ht < 4; ++ht)                                      \
                _Pragma("unroll")                                               \
                for (int r2 = 0; r2 < 2; ++r2)                                  \
                    acc1[ht][r2] = __builtin_amdgcn_mfma_f32_16x16x32_bf16(     \
                        w1f[ht][kk], xb[r2], acc1[ht][r2], 0, 0, 0);            \
        }                                                                       \
        _Pragma("unroll")                                                       \
        for (int ht = 0; ht < 2; ++ht)                                          \
            _Pragma("unroll")                                                   \
            for (int r2 = 0; r2 < 2; ++r2) {                                    \
                uintx2 hp = { pk2(tanh_pre(acc1[ht][r2][0]), tanh_pre(acc1[ht][r2][1])), \
                              pk2(tanh_pre(acc1[ht][r2][2]), tanh_pre(acc1[ht][r2][3])) }; \
                *(uintx2*)&Hs[(RT0 + r2) * 16 + l15][(hb0 >> 1) + ht * 16 + q * 4] = hp; \
            }                                                                   \
        _Pragma("unroll")                                                       \
        for (int ht = 2; ht < 4; ++ht)                                          \
            _Pragma("unroll")                                                   \
            for (int r2 = 0; r2 < 2; ++r2)                                      \
                *(floatx4*)&Raw[S][r2 * 16 + l15][(hb0 >> 1) + (ht - 2) * 16 + q * 4] = acc1[ht][r2]; \
    }

// ---- G2 consumer: stream SI, tile rt = SI*2+rt_rel, d cols dp..dp+32.
// Even kk-blocks: hb from compact Hs. Odd kk-blocks: load raw f32 from
// Raw[SI], tanh+pack in registers (identical values to R6's Hs path).
// Accumulation order kk=0..7 preserved.
#define DO_G2(SI)                                                               \
    {                                                                           \
        const int rt = (SI) * 2 + rt_rel;                                       \
        const unsigned short* hrow = &Hs[rt * 16 + l15][0];                     \
        const float* rrow = &Raw[SI][rt_rel * 16 + l15][0];                     \
        floatx4 acc2a, acc2b;                                                   \
        {                                                                       \
            short8 hb = *(const short8*)&hrow[q * 8];                           \
            acc2a = __builtin_amdgcn_mfma_f32_16x16x32_bf16(                    \
                w2f[0][0], hb, unpk4(fpk[SI][0]), 0, 0, 0);                     \
            acc2b = __builtin_amdgcn_mfma_f32_16x16x32_bf16(                    \
                w2f[1][0], hb, unpk4(fpk[SI][1]), 0, 0, 0);                     \
        }                                                                       \
        _Pragma("unroll")                                                       \
        for (int m = 0; m < 4; ++m) {                                           \
            /* odd kk = 2m+1: register tanh from Raw */                         \
            floatx4 v0 = *(const floatx4*)&rrow[m * 32 + q * 8];                \
            floatx4 v1 = *(const floatx4*)&rrow[m * 32 + q * 8 + 4];            \
            unsigned ub[4];                                                     \
            ub[0] = pk2(tanh_pre(v0[0]), tanh_pre(v0[1]));                      \
            ub[1] = pk2(tanh_pre(v0[2]), tanh_pre(v0[3]));                      \
            ub[2] = pk2(tanh_pre(v1[0]), tanh_pre(v1[1]));                      \
            ub[3] = pk2(tanh_pre(v1[2]), tanh_pre(v1[3]));                      \
            short8 hbr; __builtin_memcpy(&hbr, ub, 16);                         \
            acc2a = __builtin_amdgcn_mfma_f32_16x16x32_bf16(                    \
                w2f[0][2 * m + 1], hbr, acc2a, 0, 0, 0);                        \
            acc2b = __builtin_amdgcn_mfma_f32_16x16x32_bf16(                    \
                w2f[1][2 * m + 1], hbr, acc2b, 0, 0, 0);                        \
            if (m < 3) {   /* even kk = 2m+2: from compact Hs */                \
                short8 hb2 = *(const short8*)&hrow[(m + 1) * 32 + q * 8];       \
                acc2a = __builtin_amdgcn_mfma_f32_16x16x32_bf16(                \
                    w2f[0][2 * m + 2], hb2, acc2a, 0, 0, 0);                    \
                acc2b = __builtin_amdgcn_mfma_f32_16x16x32_bf16(                \
                    w2f[1][2 * m + 2], hb2, acc2b, 0, 0, 0);                    \
            }                                                                   \
        }                                                                       \
        _Pragma("unroll")                                                       \
        for (int h = 0; h < 2; ++h) {                                           \
            floatx4 kv = (h == 0 ? acc2a : acc2b) * dlt;                        \
            floatx4 xe;                                                         \
            if (sub == 0)      { kacc[SI][h] = kv;            xe = xv[SI][h] + 0.25f * kv; } \
            else if (sub == 1) { kacc[SI][h] += 2.0f * kv;    xe = xv[SI][h] + 0.25f * kv; } \
            else if (sub == 2) { kacc[SI][h] += 2.0f * kv;    xe = xv[SI][h] + 0.5f  * kv; } \
            else               { xv[SI][h] += (kacc[SI][h] + kv) * (1.0f / 12.0f); xe = xv[SI][h]; } \
            uintx2 px = { pk2(xe[0], xe[1]), pk2(xe[2], xe[3]) };               \
            *(uintx2*)&Atile[rt * 16 + l15][dp + h * 16 + q * 4] = px;          \
        }                                                                       \
        if (ii == 7) {                                                          \
            const size_t ob = (size_t)((sb * 8 + blk) * 2048 + n0 + rt * 16 + l15) * 64; \
            _Pragma("unroll")                                                   \
            for (int h = 0; h < 2; ++h)                                         \
                *(floatx4*)(out + ob + dp + h * 16 + q * 4) = xv[SI][h];        \
        }                                                                       \
    }

    if (w < 4) {
        // ================= G1 producer waves =================
        const int hb0 = w * 64;
        short8 w1f[4][3];
#pragma unroll
        for (int ht = 0; ht < 4; ++ht)
#pragma unroll
            for (int kk = 0; kk < 3; ++kk) {
                short8 f;
#pragma unroll
                for (int j = 0; j < 8; ++j) {
                    int k = kk * 32 + q * 8 + j;
                    int hc = hb0 + ht * 16 + l15;
                    f[j] = (short)bf16rne(w1_in[k * 256 + hc] * LOG2E_X2);
                }
                w1f[ht][kk] = f;
            }
        floatx4 bbf[4];
#pragma unroll
        for (int ht = 0; ht < 4; ++ht) {
            floatx4 v = *(const floatx4*)(b1_in + hb0 + ht * 16 + q * 4);
            bbf[ht] = v * LOG2E_X2;
        }

        __syncthreads();                 // init barrier: Atile-x/Phi ready
        DO_G1P(0, 0)                     // prologue: Hs(A,0) kept + Raw[0]
#pragma unroll 1
        for (int it = 0; it < 64; ++it) {
            __syncthreads();             // HsA/Raw[0](it), AtileB(it) published
            DO_G1P(2, 1)                 // stream B, substep it
            __syncthreads();             // HsB/Raw[1](it), AtileA(it+1) published
            if (it < 63) { DO_G1P(0, 0) }// stream A, substep it+1
        }
    } else {
        // ================= G2 consumer waves =================
        const int g2 = w - 4;
        const int rt_rel = g2 >> 1;
        const int dp = (g2 & 1) * 32;
        short8 w2f[2][8];                // [d-half][kk]
#pragma unroll
        for (int h = 0; h < 2; ++h)
#pragma unroll
            for (int kk = 0; kk < 8; ++kk) {
                short8 f;
#pragma unroll
                for (int j = 0; j < 8; ++j) {
                    int k = kk * 32 + q * 8 + j;
                    f[j] = (short)bf16rne(w2_in[k * 64 + dp + h * 16 + l15]);
                }
                w2f[h][kk] = f;
            }

        floatx4 xv[2][2], kacc[2][2];
        uintx2 fpk[2][2];                // b2+bfr, bf16-packed C-seeds
#pragma unroll
        for (int si = 0; si < 2; ++si) {
            const int rt = si * 2 + rt_rel;
            const int rg = rowg0 + rt * 16 + l15;
#pragma unroll
            for (int h = 0; h < 2; ++h) {
                const int dh = dp + h * 16 + q * 4;
                xv[si][h] = *(const floatx4*)(s_in + rg * 64 + dh);
                floatx4 fb = *(const floatx4*)(b2_in + dh)
                           + *(const floatx4*)(bfr_in + rg * 64 + dh);
                fpk[si][h] = (uintx2){ pk2(fb[0], fb[1]), pk2(fb[2], fb[3]) };
                uintx2 px = { pk2(xv[si][h][0], xv[si][h][1]),
                              pk2(xv[si][h][2], xv[si][h][3]) };
                *(uintx2*)&Atile[rt * 16 + l15][dh] = px;
            }
        }

        __syncthreads();                 // init barrier: Atile-x/Phi ready
#pragma unroll 1
        for (int blk = 0; blk < 8; ++blk) {
            const float dlt = dls[blk];
#pragma unroll 1
            for (int ii = 0; ii < 8; ++ii) {
                const int sub = ii & 3;
                __syncthreads();         // HsA/Raw[0](i), AtileB(i) published
                DO_G2(0)                 // stream A: GEMM2 (+reg tanh) + RK4
                __syncthreads();         // HsB/Raw[1](i), AtileA(i+1) published
                DO_G2(1)                 // stream B: GEMM2 (+reg tanh) + RK4
            }
        }
    }
#undef DO_G1P
#undef DO_G2
}

extern "C" void kernel_launch(void* const* d_in, const int* in_sizes, int n_in,
                              void* d_out, int out_size, void* d_ws, size_t ws_size,
                              hipStream_t stream) {
    const float* s_in  = (const float*)d_in[0];
    const float* t_in  = (const float*)d_in[1];
    const float* phi   = (const float*)d_in[2];
    const float* bfr   = (const float*)d_in[3];
    const float* w1    = (const float*)d_in[4];
    const float* b1    = (const float*)d_in[5];
    const float* w2    = (const float*)d_in[6];
    const float* b2    = (const float*)d_in[7];
    ode_mfma<<<512, 512, 0, stream>>>(s_in, t_in, phi, bfr, w1, b1, w2, b2, (float*)d_out);
}

// Round 8
// 303.761 us; speedup vs baseline: 1.5124x; 1.2138x over previous
//
#include <hip/hip_runtime.h>

typedef short  short8   __attribute__((ext_vector_type(8)));
typedef float  floatx4  __attribute__((ext_vector_type(4)));
typedef unsigned int uintx2 __attribute__((ext_vector_type(2)));

#define LOG2E_X2 2.8853900817779268f

// Inputs pre-scaled by 2*log2(e) (folded into W1/b1): tanh(a)=1-2/(exp2(y)+1).
__device__ __forceinline__ float tanh_pre(float y) {
    float e = __builtin_amdgcn_exp2f(y);
    return 1.0f - 2.0f * __builtin_amdgcn_rcpf(1.0f + e);
}

__device__ __forceinline__ unsigned short bf16rne(float f) {   // setup only
    unsigned u = __float_as_uint(f);
    u += 0x7FFFu + ((u >> 16) & 1u);
    return (unsigned short)(u >> 16);
}

// RNE-pack two f32 -> dword of 2 bf16 (lo=a, hi=b).
#if __has_builtin(__builtin_amdgcn_cvt_pk_bf16_f32)
__device__ __forceinline__ unsigned pk2(float a, float b) {
    auto r = __builtin_amdgcn_cvt_pk_bf16_f32(a, b);
    unsigned u; __builtin_memcpy(&u, &r, 4);
    return u;
}
#else
__device__ __forceinline__ unsigned pk2(float a, float b) {
    unsigned r;
    asm("v_cvt_pk_bf16_f32 %0, %1, %2" : "=v"(r) : "v"(a), "v"(b));
    return r;
}
#endif

// Unpack 4 bf16 (packed lo/hi per dword) -> floatx4, exact.
__device__ __forceinline__ floatx4 unpk4(uintx2 u) {
    floatx4 r;
    r[0] = __uint_as_float(u.x << 16);
    r[1] = __uint_as_float(u.x & 0xffff0000u);
    r[2] = __uint_as_float(u.y << 16);
    r[3] = __uint_as_float(u.y & 0xffff0000u);
    return r;
}

// Round 11: EXACT R6 kernel (best: 252us dispatch) + ONE change: co-resident-
// block phase stagger. The two blocks sharing a CU run identical barrier
// rhythms; their G1 tanh bursts collide on the shared VALU/trans pipes while
// both idle together in MFMA/LDS phases (R6: VALU 58%, MFMA 30%, ~40% idle,
// nothing saturated). A one-time ~2400-cyc sleep on one block of each pair
// offsets the rhythms ~half an interval. (bid>>8 ^ bid)&1 separates the pair
// under either pairing hypothesis: (i,i+256) round-robin-XCD or (2i,2i+1).
// R10's lesson (kept): tanh rebalance onto G2 duplicates work (VALU is
// SIMD-co-limiting, +31% VALU cycles measured) — don't.
// Arithmetic identical to R6 -> bit-identical output (absmax 0.03125).
__global__ __launch_bounds__(512, 4) void ode_mfma(
    const float* __restrict__ s_in,  const float* __restrict__ t_in,
    const float* __restrict__ phi_in,const float* __restrict__ bfr_in,
    const float* __restrict__ w1_in, const float* __restrict__ b1_in,
    const float* __restrict__ w2_in, const float* __restrict__ b2_in,
    float* __restrict__ out)
{
    // Phase stagger (the ONE change vs R6):
    if (((blockIdx.x >> 8) ^ blockIdx.x) & 1) __builtin_amdgcn_s_sleep(37);

    const int tid  = threadIdx.x;
    const int w    = tid >> 6;         // wave 0..7
    const int lane = tid & 63;
    const int l15  = lane & 15;
    const int q    = lane >> 4;
    const int wg   = blockIdx.x;
    const int sb   = wg >> 5;
    const int n0   = (wg & 31) << 6;
    const int rowg0 = sb * 2048 + n0;

    __shared__ __align__(16) unsigned short Atile[64][104];
    __shared__ __align__(16) unsigned short Hs[64][264];
    __shared__ float dls[8];

    // Phi -> Atile cols 64..95 (all 512 threads, one floatx4 each; written once)
    {
        int row = tid >> 3, cc = tid & 7;
        floatx4 p = *(const floatx4*)(phi_in + (rowg0 + row) * 32 + cc * 4);
        uintx2 px = { pk2(p[0], p[1]), pk2(p[2], p[3]) };
        *(uintx2*)&Atile[row][64 + cc * 4] = px;
    }
    if (tid < 8) dls[tid] = t_in[sb * 9 + tid + 1] - t_in[sb * 9 + tid];

// ---- G1 producer: stream row-tiles (RT0, RT0+1), this wave's 64 h-channels.
// Reads Atile, writes Hs[.][hb0..hb0+64). 24 MFMA, 6 ds_read_b128, 8 ds_write_b64.
#define DO_G1(RT0)                                                              \
    {                                                                           \
        floatx4 acc1[4][2];                                                     \
        {                                                                       \
            short8 xb[2];                                                       \
            _Pragma("unroll")                                                   \
            for (int r2 = 0; r2 < 2; ++r2)                                      \
                xb[r2] = *(const short8*)&Atile[(RT0 + r2) * 16 + l15][q * 8];  \
            _Pragma("unroll")                                                   \
            for (int ht = 0; ht < 4; ++ht)                                      \
                _Pragma("unroll")                                               \
                for (int r2 = 0; r2 < 2; ++r2)                                  \
                    acc1[ht][r2] = __builtin_amdgcn_mfma_f32_16x16x32_bf16(     \
                        w1f[ht][0], xb[r2], bbf[ht], 0, 0, 0);                  \
        }                                                                       \
        _Pragma("unroll")                                                       \
        for (int kk = 1; kk < 3; ++kk) {                                        \
            short8 xb[2];                                                       \
            _Pragma("unroll")                                                   \
            for (int r2 = 0; r2 < 2; ++r2)                                      \
                xb[r2] = *(const short8*)&Atile[(RT0 + r2) * 16 + l15][kk * 32 + q * 8]; \
            _Pragma("unroll")                                                   \
            for (int ht = 0; ht < 4; ++ht)                                      \
                _Pragma("unroll")                                               \
                for (int r2 = 0; r2 < 2; ++r2)                                  \
                    acc1[ht][r2] = __builtin_amdgcn_mfma_f32_16x16x32_bf16(     \
                        w1f[ht][kk], xb[r2], acc1[ht][r2], 0, 0, 0);            \
        }                                                                       \
        _Pragma("unroll")                                                       \
        for (int ht = 0; ht < 4; ++ht)                                          \
            _Pragma("unroll")                                                   \
            for (int r2 = 0; r2 < 2; ++r2) {                                    \
                uintx2 hp = { pk2(tanh_pre(acc1[ht][r2][0]), tanh_pre(acc1[ht][r2][1])), \
                              pk2(tanh_pre(acc1[ht][r2][2]), tanh_pre(acc1[ht][r2][3])) }; \
                *(uintx2*)&Hs[(RT0 + r2) * 16 + l15][hb0 + ht * 16 + q * 4] = hp; \
            }                                                                   \
    }

// ---- G2 consumer: stream SI, this wave's tile rt = SI*2+rt_rel, d cols
// dp..dp+32. Reads Hs (8 b128, each feeds 2 MFMA), RK4 epilogue, writes Atile.
#define DO_G2(SI)                                                               \
    {                                                                           \
        const int rt = (SI) * 2 + rt_rel;                                       \
        const unsigned short* hrow = &Hs[rt * 16 + l15][0];                     \
        floatx4 acc2a, acc2b;                                                   \
        {                                                                       \
            short8 hb = *(const short8*)&hrow[q * 8];                           \
            acc2a = __builtin_amdgcn_mfma_f32_16x16x32_bf16(                    \
                w2f[0][0], hb, unpk4(fpk[SI][0]), 0, 0, 0);                     \
            acc2b = __builtin_amdgcn_mfma_f32_16x16x32_bf16(                    \
                w2f[1][0], hb, unpk4(fpk[SI][1]), 0, 0, 0);                     \
        }                                                                       \
        _Pragma("unroll")                                                       \
        for (int kk = 1; kk < 8; ++kk) {                                        \
            short8 hb = *(const short8*)&hrow[kk * 32 + q * 8];                 \
            acc2a = __builtin_amdgcn_mfma_f32_16x16x32_bf16(                    \
                w2f[0][kk], hb, acc2a, 0, 0, 0);                                \
            acc2b = __builtin_amdgcn_mfma_f32_16x16x32_bf16(                    \
                w2f[1][kk], hb, acc2b, 0, 0, 0);                                \
        }                                                                       \
        _Pragma("unroll")                                                       \
        for (int h = 0; h < 2; ++h) {                                           \
            floatx4 kv = (h == 0 ? acc2a : acc2b) * dlt;                        \
            floatx4 xe;                                                         \
            if (sub == 0)      { kacc[SI][h] = kv;            xe = xv[SI][h] + 0.25f * kv; } \
            else if (sub == 1) { kacc[SI][h] += 2.0f * kv;    xe = xv[SI][h] + 0.25f * kv; } \
            else if (sub == 2) { kacc[SI][h] += 2.0f * kv;    xe = xv[SI][h] + 0.5f  * kv; } \
            else               { xv[SI][h] += (kacc[SI][h] + kv) * (1.0f / 12.0f); xe = xv[SI][h]; } \
            uintx2 px = { pk2(xe[0], xe[1]), pk2(xe[2], xe[3]) };               \
            *(uintx2*)&Atile[rt * 16 + l15][dp + h * 16 + q * 4] = px;          \
        }                                                                       \
        if (ii == 7) {                                                          \
            const size_t ob = (size_t)((sb * 8 + blk) * 2048 + n0 + rt * 16 + l15) * 64; \
            _Pragma("unroll")                                                   \
            for (int h = 0; h < 2; ++h)                                         \
                *(floatx4*)(out + ob + dp + h * 16 + q * 4) = xv[SI][h];        \
        }                                                                       \
    }

    if (w < 4) {
        // ================= G1 producer waves =================
        const int hb0 = w * 64;
        short8 w1f[4][3];
#pragma unroll
        for (int ht = 0; ht < 4; ++ht)
#pragma unroll
            for (int kk = 0; kk < 3; ++kk) {
                short8 f;
#pragma unroll
                for (int j = 0; j < 8; ++j) {
                    int k = kk * 32 + q * 8 + j;
                    int hc = hb0 + ht * 16 + l15;
                    f[j] = (short)bf16rne(w1_in[k * 256 + hc] * LOG2E_X2);
                }
                w1f[ht][kk] = f;
            }
        floatx4 bbf[4];
#pragma unroll
        for (int ht = 0; ht < 4; ++ht) {
            floatx4 v = *(const floatx4*)(b1_in + hb0 + ht * 16 + q * 4);
            bbf[ht] = v * LOG2E_X2;
        }

        __syncthreads();                 // init barrier: Atile-x/Phi ready
        DO_G1(0)                         // prologue: HsA(0)
#pragma unroll 1
        for (int it = 0; it < 64; ++it) {
            __syncthreads();             // HsA(it)/AtileB(it) published
            DO_G1(2)                     // stream B, substep it
            __syncthreads();             // HsB(it)/AtileA(it+1) published
            if (it < 63) { DO_G1(0) }    // stream A, substep it+1
        }
    } else {
        // ================= G2 consumer waves =================
        const int g = w - 4;
        const int rt_rel = g >> 1;
        const int dp = (g & 1) * 32;
        short8 w2f[2][8];                // [d-half][kk]
#pragma unroll
        for (int h = 0; h < 2; ++h)
#pragma unroll
            for (int kk = 0; kk < 8; ++kk) {
                short8 f;
#pragma unroll
                for (int j = 0; j < 8; ++j) {
                    int k = kk * 32 + q * 8 + j;
                    f[j] = (short)bf16rne(w2_in[k * 64 + dp + h * 16 + l15]);
                }
                w2f[h][kk] = f;
            }

        floatx4 xv[2][2], kacc[2][2];
        uintx2 fpk[2][2];                // b2+bfr, bf16-packed C-seeds
#pragma unroll
        for (int si = 0; si < 2; ++si) {
            const int rt = si * 2 + rt_rel;
            const int rg = rowg0 + rt * 16 + l15;
#pragma unroll
            for (int h = 0; h < 2; ++h) {
                const int dh = dp + h * 16 + q * 4;
                xv[si][h] = *(const floatx4*)(s_in + rg * 64 + dh);
                floatx4 fb = *(const floatx4*)(b2_in + dh)
                           + *(const floatx4*)(bfr_in + rg * 64 + dh);
                fpk[si][h] = (uintx2){ pk2(fb[0], fb[1]), pk2(fb[2], fb[3]) };
                uintx2 px = { pk2(xv[si][h][0], xv[si][h][1]),
                              pk2(xv[si][h][2], xv[si][h][3]) };
                *(uintx2*)&Atile[rt * 16 + l15][dh] = px;
            }
        }

        __syncthreads();                 // init barrier: Atile-x/Phi ready
#pragma unroll 1
        for (int blk = 0; blk < 8; ++blk) {
            const float dlt = dls[blk];
#pragma unroll 1
            for (int ii = 0; ii < 8; ++ii) {
                const int sub = ii & 3;
                __syncthreads();         // HsA(i)/AtileB(i) published
                DO_G2(0)                 // stream A: GEMM2 + RK4 epilogue
                __syncthreads();         // HsB(i)/AtileA(i+1) published
                DO_G2(1)                 // stream B: GEMM2 + RK4 epilogue
            }
        }
    }
#undef DO_G1
#undef DO_G2
}

extern "C" void kernel_launch(void* const* d_in, const int* in_sizes, int n_in,
                              void* d_out, int out_size, void* d_ws, size_t ws_size,
                              hipStream_t stream) {
    const float* s_in  = (const float*)d_in[0];
    const float* t_in  = (const float*)d_in[1];
    const float* phi   = (const float*)d_in[2];
    const float* bfr   = (const float*)d_in[3];
    const float* w1    = (const float*)d_in[4];
    const float* b1    = (const float*)d_in[5];
    const float* w2    = (const float*)d_in[6];
    const float* b2    = (const float*)d_in[7];
    ode_mfma<<<512, 512, 0, stream>>>(s_in, t_in, phi, bfr, w1, b1, w2, b2, (float*)d_out);
}